// Round 1
// baseline (343.811 us; speedup 1.0000x reference)
//
#include <hip/hip_runtime.h>

#define B   2
#define N   32768
#define NC  1024
#define S   32
#define NSP (NC * S)   // 32768

#define K2 8           // sphere points per thread in k_sp2p
#define CH 32          // xyz chunks
#define CHUNK (N / CH) // 1024

// ws layout (floats): [0..1]=acc_p[b], [2..3]=acc_c[b], [4..4+B*NSP)=minsq (uint bits)

__global__ __launch_bounds__(256) void init_ws(unsigned* __restrict__ minsq,
                                               float* __restrict__ acc) {
    int i = blockIdx.x * 256 + threadIdx.x;
    if (i < 4) acc[i] = 0.0f;
    if (i < B * NSP) minsq[i] = 0x7F800000u;  // +inf bits
}

// Part 1: per xyz point, nearest center -> mean(max(cd - r, 0))
__global__ __launch_bounds__(256) void k_p2c(const float* __restrict__ centers,
                                             const float* __restrict__ radius,
                                             const float* __restrict__ xyz,
                                             float* __restrict__ acc_p) {
    __shared__ float4 c4[NC];   // x, y, z, h=0.5*|c|^2
    __shared__ float  rad[NC];
    const int b   = blockIdx.y;
    const int tid = threadIdx.x;

    const float* cb = centers + (size_t)b * NC * 3;
    for (int g = tid; g < NC / 4; g += 256) {
        float4 f0 = ((const float4*)cb)[g * 3 + 0];
        float4 f1 = ((const float4*)cb)[g * 3 + 1];
        float4 f2 = ((const float4*)cb)[g * 3 + 2];
        float x0 = f0.x, y0 = f0.y, z0 = f0.z;
        float x1 = f0.w, y1 = f1.x, z1 = f1.y;
        float x2 = f1.z, y2 = f1.w, z2 = f2.x;
        float x3 = f2.y, y3 = f2.z, z3 = f2.w;
        c4[g * 4 + 0] = make_float4(x0, y0, z0, 0.5f * (x0 * x0 + y0 * y0 + z0 * z0));
        c4[g * 4 + 1] = make_float4(x1, y1, z1, 0.5f * (x1 * x1 + y1 * y1 + z1 * z1));
        c4[g * 4 + 2] = make_float4(x2, y2, z2, 0.5f * (x2 * x2 + y2 * y2 + z2 * z2));
        c4[g * 4 + 3] = make_float4(x3, y3, z3, 0.5f * (x3 * x3 + y3 * y3 + z3 * z3));
    }
    const float* rb = radius + (size_t)b * NC;
    for (int g = tid; g < NC / 4; g += 256) {
        float4 r4 = ((const float4*)rb)[g];
        rad[g * 4 + 0] = r4.x; rad[g * 4 + 1] = r4.y;
        rad[g * 4 + 2] = r4.z; rad[g * 4 + 3] = r4.w;
    }
    __syncthreads();

    const int pi = blockIdx.x * 256 + tid;
    const float* p = xyz + ((size_t)b * N + pi) * 3;
    const float px = p[0], py = p[1], pz = p[2];
    const float pp = px * px + py * py + pz * pz;

    float tmin = 1e30f;
    int   imin = 0;
    #pragma unroll 4
    for (int c = 0; c < NC; ++c) {
        float4 q = c4[c];
        float  t = q.w - px * q.x - py * q.y - pz * q.z;
        if (t < tmin) { tmin = t; imin = c; }   // strict <: first-occurrence argmin
    }
    const float sq = 2.0f * tmin + pp;
    const float cd = sqrtf(fmaxf(sq, 1e-12f));
    float val = fmaxf(cd - rad[imin], 0.0f);    // |min(r - cd, 0)|

    #pragma unroll
    for (int o = 32; o > 0; o >>= 1) val += __shfl_down(val, o);
    __shared__ float wsum[4];
    if ((tid & 63) == 0) wsum[tid >> 6] = val;
    __syncthreads();
    if (tid == 0) atomicAdd(&acc_p[b], wsum[0] + wsum[1] + wsum[2] + wsum[3]);
}

// Part 2: per sphere point, min squared-dist over an xyz chunk -> atomicMin
__global__ __launch_bounds__(256) void k_sp2p(const float* __restrict__ xyz,
                                              const float* __restrict__ sp,
                                              unsigned* __restrict__ minsq) {
    __shared__ float4 q4[CHUNK];  // x, y, z, h=0.5*|q|^2
    const int b     = blockIdx.z;
    const int chunk = blockIdx.y;
    const int tid   = threadIdx.x;

    const float* xb = xyz + ((size_t)b * N + (size_t)chunk * CHUNK) * 3;
    for (int g = tid; g < CHUNK / 4; g += 256) {
        float4 f0 = ((const float4*)xb)[g * 3 + 0];
        float4 f1 = ((const float4*)xb)[g * 3 + 1];
        float4 f2 = ((const float4*)xb)[g * 3 + 2];
        float x0 = f0.x, y0 = f0.y, z0 = f0.z;
        float x1 = f0.w, y1 = f1.x, z1 = f1.y;
        float x2 = f1.z, y2 = f1.w, z2 = f2.x;
        float x3 = f2.y, y3 = f2.z, z3 = f2.w;
        q4[g * 4 + 0] = make_float4(x0, y0, z0, 0.5f * (x0 * x0 + y0 * y0 + z0 * z0));
        q4[g * 4 + 1] = make_float4(x1, y1, z1, 0.5f * (x1 * x1 + y1 * y1 + z1 * z1));
        q4[g * 4 + 2] = make_float4(x2, y2, z2, 0.5f * (x2 * x2 + y2 * y2 + z2 * z2));
        q4[g * 4 + 3] = make_float4(x3, y3, z3, 0.5f * (x3 * x3 + y3 * y3 + z3 * z3));
    }

    const int spbase = blockIdx.x * (256 * K2) + tid;  // within batch, stride-256 per k
    const float* sb = sp + (size_t)b * NSP * 3;
    float sx[K2], sy[K2], sz[K2], sh[K2], tm[K2];
    #pragma unroll
    for (int k = 0; k < K2; ++k) {
        const int i = spbase + k * 256;
        sx[k] = sb[i * 3 + 0];
        sy[k] = sb[i * 3 + 1];
        sz[k] = sb[i * 3 + 2];
        sh[k] = sx[k] * sx[k] + sy[k] * sy[k] + sz[k] * sz[k];  // full |p|^2
        tm[k] = 1e30f;
    }
    __syncthreads();

    #pragma unroll 4
    for (int j = 0; j < CHUNK; ++j) {
        const float4 q = q4[j];   // broadcast read, conflict-free
        #pragma unroll
        for (int k = 0; k < K2; ++k) {
            float t = q.w - sx[k] * q.x - sy[k] * q.y - sz[k] * q.z;  // 3 FMA
            tm[k] = fminf(tm[k], t);
        }
    }

    #pragma unroll
    for (int k = 0; k < K2; ++k) {
        const int i = spbase + k * 256;
        const float sq = fmaxf(2.0f * tm[k] + sh[k], 0.0f);  // >=0 for uint-order trick
        atomicMin(&minsq[(size_t)b * NSP + i], __float_as_uint(sq));
    }
}

// Part 3: sqrt, max over groups of S, per-batch sum of maxes
__global__ __launch_bounds__(256) void k_groupmax(const unsigned* __restrict__ minsq,
                                                  float* __restrict__ acc_c) {
    const int g = blockIdx.x * 256 + threadIdx.x;  // group id in [0, B*NC)
    const int b = g / NC;                          // uniform per wave
    const unsigned* base = minsq + (size_t)g * S;
    float mx = 0.0f;
    #pragma unroll
    for (int i = 0; i < S; ++i) {
        const float sq = __uint_as_float(base[i]);
        const float cd = sqrtf(fmaxf(sq, 1e-12f));
        mx = fmaxf(mx, cd);
    }
    #pragma unroll
    for (int o = 32; o > 0; o >>= 1) mx += __shfl_down(mx, o);  // sum of group-maxes
    if ((threadIdx.x & 63) == 0) atomicAdd(&acc_c[b], mx);
}

__global__ void k_final(const float* __restrict__ acc, float* __restrict__ out) {
    float r = 0.0f;
    for (int b = 0; b < B; ++b)
        r += acc[2 + b] / (float)NC + acc[b] / (float)N;
    out[0] = r / (float)B;
}

extern "C" void kernel_launch(void* const* d_in, const int* in_sizes, int n_in,
                              void* d_out, int out_size, void* d_ws, size_t ws_size,
                              hipStream_t stream) {
    const float* centers = (const float*)d_in[0];
    const float* radius  = (const float*)d_in[1];
    const float* xyz     = (const float*)d_in[2];
    const float* sp      = (const float*)d_in[3];
    float* out = (float*)d_out;

    float*    acc   = (float*)d_ws;             // 4 floats
    unsigned* minsq = (unsigned*)d_ws + 4;      // B*NSP uints (256 KB + 16 B total)

    hipLaunchKernelGGL(init_ws, dim3((B * NSP + 255) / 256), dim3(256), 0, stream,
                       minsq, acc);
    hipLaunchKernelGGL(k_p2c, dim3(N / 256, B), dim3(256), 0, stream,
                       centers, radius, xyz, acc);
    hipLaunchKernelGGL(k_sp2p, dim3(NSP / (256 * K2), CH, B), dim3(256), 0, stream,
                       xyz, sp, minsq);
    hipLaunchKernelGGL(k_groupmax, dim3(B * NC / 256), dim3(256), 0, stream,
                       minsq, acc + 2);
    hipLaunchKernelGGL(k_final, dim3(1), dim3(1), 0, stream, acc, out);
}

// Round 2
// 208.650 us; speedup vs baseline: 1.6478x; 1.6478x over previous
//
#include <hip/hip_runtime.h>

#define B   2
#define N   32768
#define NC  1024
#define S   32
#define NSP (NC * S)   // 32768

#define CHUNK   2048            // xyz rows staged per block
#define NCHUNK  (N / CHUNK)     // 16
#define WAVES   8
#define BLK     (WAVES * 64)    // 512
#define COLS_PER_BLOCK (WAVES * 32)       // 256
#define COLTILES (NSP / COLS_PER_BLOCK)   // 128

typedef __attribute__((ext_vector_type(8)))  short short8v;
typedef __attribute__((ext_vector_type(16))) float f32x16;
typedef const __attribute__((address_space(1))) void gvoid_t;
typedef __attribute__((address_space(3))) void svoid_t;

// ws layout: Afrag (2 MB) | minsq (256 KB) | acc (4 floats)
#define WS_AFRAG_USHORTS ((size_t)B * N * 16)
#define WS_MINSQ_OFF     (WS_AFRAG_USHORTS)              // in ushort units -> cast
// we compute pointers in kernel_launch instead.

static __device__ __forceinline__ unsigned short f2b(float x) {
    unsigned u = __float_as_uint(x);
    unsigned r = (u + 0x7FFFu + ((u >> 16) & 1u)) >> 16;   // RNE
    return (unsigned short)r;
}
static __device__ __forceinline__ float b2f(unsigned short u) {
    return __uint_as_float(((unsigned)u) << 16);
}

__global__ __launch_bounds__(256) void init_ws(unsigned* __restrict__ minsq,
                                               float* __restrict__ acc) {
    int i = blockIdx.x * 256 + threadIdx.x;
    if (i < 4) acc[i] = 0.0f;
    if (i < B * NSP) minsq[i] = 0x7F800000u;  // +inf bits
}

// Build A-fragments for xyz points, in exact mfma_32x32x16 A-operand order.
// Per row j (xyz point q), K slots: [-qxh,-qyh,-qzh, -qxl,-qyl,-qzl, -qxh,-qyh]
// (lane j&31) and [-qzh, h_hi, h_lo, 0...] (lane 32+(j&31)), h = 0.5|q|^2.
__global__ __launch_bounds__(256) void prep(const float* __restrict__ xyz,
                                            unsigned short* __restrict__ Afrag) {
    int i = blockIdx.x * 256 + threadIdx.x;   // [0, B*N)
    const float* q = xyz + (size_t)i * 3;
    float qx = q[0], qy = q[1], qz = q[2];
    float h = 0.5f * (qx * qx + qy * qy + qz * qz);
    unsigned short xh = f2b(-qx), yh = f2b(-qy), zh = f2b(-qz);
    unsigned short xl = f2b(-qx - b2f(xh));
    unsigned short yl = f2b(-qy - b2f(yh));
    unsigned short zl = f2b(-qz - b2f(zh));
    unsigned short hh = f2b(h), hl = f2b(h - b2f(hh));

    int b = i >> 15, j = i & (N - 1);
    int tile = j >> 5, r = j & 31;
    unsigned short* base = Afrag + ((size_t)b * N + (size_t)tile * 32) * 16;
    uint4 s0, s1;
    s0.x = (unsigned)xh | ((unsigned)yh << 16);
    s0.y = (unsigned)zh | ((unsigned)xl << 16);
    s0.z = (unsigned)yl | ((unsigned)zl << 16);
    s0.w = (unsigned)xh | ((unsigned)yh << 16);
    s1.x = (unsigned)zh | ((unsigned)hh << 16);
    s1.y = (unsigned)hl;
    s1.z = 0u; s1.w = 0u;
    *(uint4*)(base + (size_t)r * 8)        = s0;   // k=0..7   lane r
    *(uint4*)(base + (size_t)(r + 32) * 8) = s1;   // k=8..15  lane r+32
}

// Part 1: per xyz point, nearest center -> mean(max(cd - r, 0))  (VALU, small)
__global__ __launch_bounds__(256) void k_p2c(const float* __restrict__ centers,
                                             const float* __restrict__ radius,
                                             const float* __restrict__ xyz,
                                             float* __restrict__ acc_p) {
    __shared__ float4 c4[NC];
    __shared__ float  rad[NC];
    const int b   = blockIdx.y;
    const int tid = threadIdx.x;

    const float* cb = centers + (size_t)b * NC * 3;
    for (int g = tid; g < NC / 4; g += 256) {
        float4 f0 = ((const float4*)cb)[g * 3 + 0];
        float4 f1 = ((const float4*)cb)[g * 3 + 1];
        float4 f2 = ((const float4*)cb)[g * 3 + 2];
        float x0 = f0.x, y0 = f0.y, z0 = f0.z;
        float x1 = f0.w, y1 = f1.x, z1 = f1.y;
        float x2 = f1.z, y2 = f1.w, z2 = f2.x;
        float x3 = f2.y, y3 = f2.z, z3 = f2.w;
        c4[g * 4 + 0] = make_float4(x0, y0, z0, 0.5f * (x0 * x0 + y0 * y0 + z0 * z0));
        c4[g * 4 + 1] = make_float4(x1, y1, z1, 0.5f * (x1 * x1 + y1 * y1 + z1 * z1));
        c4[g * 4 + 2] = make_float4(x2, y2, z2, 0.5f * (x2 * x2 + y2 * y2 + z2 * z2));
        c4[g * 4 + 3] = make_float4(x3, y3, z3, 0.5f * (x3 * x3 + y3 * y3 + z3 * z3));
    }
    const float* rb = radius + (size_t)b * NC;
    for (int g = tid; g < NC / 4; g += 256) {
        float4 r4 = ((const float4*)rb)[g];
        rad[g * 4 + 0] = r4.x; rad[g * 4 + 1] = r4.y;
        rad[g * 4 + 2] = r4.z; rad[g * 4 + 3] = r4.w;
    }
    __syncthreads();

    const int pi = blockIdx.x * 256 + tid;
    const float* p = xyz + ((size_t)b * N + pi) * 3;
    const float px = p[0], py = p[1], pz = p[2];
    const float pp = px * px + py * py + pz * pz;

    float tmin = 1e30f;
    int   imin = 0;
    #pragma unroll 4
    for (int c = 0; c < NC; ++c) {
        float4 q = c4[c];
        float  t = q.w - px * q.x - py * q.y - pz * q.z;
        if (t < tmin) { tmin = t; imin = c; }
    }
    const float sq = 2.0f * tmin + pp;
    const float cd = sqrtf(fmaxf(sq, 1e-12f));
    float val = fmaxf(cd - rad[imin], 0.0f);

    #pragma unroll
    for (int o = 32; o > 0; o >>= 1) val += __shfl_down(val, o);
    __shared__ float wsum[4];
    if ((tid & 63) == 0) wsum[tid >> 6] = val;
    __syncthreads();
    if (tid == 0) atomicAdd(&acc_p[b], wsum[0] + wsum[1] + wsum[2] + wsum[3]);
}

// Part 2: MFMA. acc = h_q - q.p per (row=xyz, col=sphere); min over rows.
__global__ __launch_bounds__(BLK) void k_sp2p(const float* __restrict__ sp,
                                              const unsigned short* __restrict__ Afrag,
                                              unsigned* __restrict__ minsq) {
    __shared__ unsigned short lds[CHUNK * 16];   // 64 KB
    const int b = blockIdx.z, chunk = blockIdx.y;
    const int tid = threadIdx.x, wid = tid >> 6, lane = tid & 63;

    // stage 64 KB of A-fragments: 8 iters x (512 lanes x 16 B)
    const char* srcb = (const char*)(Afrag + ((size_t)b * N + (size_t)chunk * CHUNK) * 16);
    #pragma unroll
    for (int it = 0; it < 8; ++it) {
        int off = it * 8192 + wid * 1024;
        __builtin_amdgcn_global_load_lds(
            (gvoid_t*)(srcb + off + lane * 16),
            (svoid_t*)((char*)lds + off), 16, 0, 0);
    }

    // B-fragment in registers (col = lane&31 sphere point of this wave's tile)
    const int gi = blockIdx.x * COLS_PER_BLOCK + wid * 32 + (lane & 31);
    const float* p = sp + ((size_t)b * NSP + gi) * 3;
    const float px = p[0], py = p[1], pz = p[2];
    const float pp = px * px + py * py + pz * pz;
    const unsigned short xh = f2b(px), yh = f2b(py), zh = f2b(pz);
    const unsigned short xl = f2b(px - b2f(xh));
    const unsigned short yl = f2b(py - b2f(yh));
    const unsigned short zl = f2b(pz - b2f(zh));
    short8v bfrag;
    if (lane < 32) {
        bfrag[0] = (short)xh; bfrag[1] = (short)yh; bfrag[2] = (short)zh;
        bfrag[3] = (short)xh; bfrag[4] = (short)yh; bfrag[5] = (short)zh;
        bfrag[6] = (short)xl; bfrag[7] = (short)yl;
    } else {
        bfrag[0] = (short)zl; bfrag[1] = (short)0x3F80; bfrag[2] = (short)0x3F80;
        bfrag[3] = 0; bfrag[4] = 0; bfrag[5] = 0; bfrag[6] = 0; bfrag[7] = 0;
    }
    f32x16 zero;
    #pragma unroll
    for (int i = 0; i < 16; ++i) zero[i] = 0.0f;

    __syncthreads();

    float run = 1e30f;
    const unsigned short* ap = lds + lane * 8;
    #pragma unroll 4
    for (int t = 0; t < CHUNK / 32; ++t) {
        short8v a = *(const short8v*)(ap + t * 512);
        f32x16 acc = __builtin_amdgcn_mfma_f32_32x32x16_bf16(a, bfrag, zero, 0, 0, 0);
        float m0 = fminf(fminf(acc[0],  acc[1]),  fminf(acc[2],  acc[3]));
        float m1 = fminf(fminf(acc[4],  acc[5]),  fminf(acc[6],  acc[7]));
        float m2 = fminf(fminf(acc[8],  acc[9]),  fminf(acc[10], acc[11]));
        float m3 = fminf(fminf(acc[12], acc[13]), fminf(acc[14], acc[15]));
        run = fminf(run, fminf(fminf(m0, m1), fminf(m2, m3)));
    }
    run = fminf(run, __shfl_xor(run, 32, 64));  // lanes l, l^32 share a col
    if (lane < 32) {
        float sq = fmaxf(2.0f * run + pp, 0.0f);
        atomicMin(&minsq[(size_t)b * NSP + gi], __float_as_uint(sq));
    }
}

// Part 3: sqrt, max over groups of S=32 (one lane-half per group), sum per batch
__global__ __launch_bounds__(256) void k_groupmax(const unsigned* __restrict__ minsq,
                                                  float* __restrict__ acc_c) {
    int i = blockIdx.x * 256 + threadIdx.x;   // [0, B*NSP)
    int b = i >> 15;                          // uniform per block (NSP=32768)
    float cd = sqrtf(fmaxf(__uint_as_float(minsq[i]), 1e-12f));
    #pragma unroll
    for (int o = 16; o > 0; o >>= 1) cd = fmaxf(cd, __shfl_xor(cd, o, 64));
    float v = ((threadIdx.x & 31) == 0) ? cd : 0.0f;
    #pragma unroll
    for (int o = 32; o > 0; o >>= 1) v += __shfl_down(v, o);
    if ((threadIdx.x & 63) == 0) atomicAdd(&acc_c[b], v);
}

__global__ void k_final(const float* __restrict__ acc, float* __restrict__ out) {
    float r = 0.0f;
    for (int b = 0; b < B; ++b)
        r += acc[2 + b] / (float)NC + acc[b] / (float)N;
    out[0] = r / (float)B;
}

extern "C" void kernel_launch(void* const* d_in, const int* in_sizes, int n_in,
                              void* d_out, int out_size, void* d_ws, size_t ws_size,
                              hipStream_t stream) {
    const float* centers = (const float*)d_in[0];
    const float* radius  = (const float*)d_in[1];
    const float* xyz     = (const float*)d_in[2];
    const float* sp      = (const float*)d_in[3];
    float* out = (float*)d_out;

    unsigned short* Afrag = (unsigned short*)d_ws;                 // 2 MB
    unsigned* minsq = (unsigned*)((char*)d_ws + WS_AFRAG_USHORTS * 2);  // 256 KB
    float* acc = (float*)((char*)minsq + (size_t)B * NSP * 4);     // 16 B

    hipLaunchKernelGGL(init_ws, dim3((B * NSP + 255) / 256), dim3(256), 0, stream,
                       minsq, acc);
    hipLaunchKernelGGL(prep, dim3(B * N / 256), dim3(256), 0, stream, xyz, Afrag);
    hipLaunchKernelGGL(k_p2c, dim3(N / 256, B), dim3(256), 0, stream,
                       centers, radius, xyz, acc);
    hipLaunchKernelGGL(k_sp2p, dim3(COLTILES, NCHUNK, B), dim3(BLK), 0, stream,
                       sp, Afrag, minsq);
    hipLaunchKernelGGL(k_groupmax, dim3(B * NSP / 256), dim3(256), 0, stream,
                       minsq, acc + 2);
    hipLaunchKernelGGL(k_final, dim3(1), dim3(1), 0, stream, acc, out);
}